// Round 3
// baseline (4057.376 us; speedup 1.0000x reference)
//
#include <hip/hip_runtime.h>
#include <hip/hip_bf16.h>

#define NB  4
#define NH  8
#define NC  16
#define ND  64
#define NN  16384
#define NG  32
#define NG3 32768
#define NKV 152
#define KEPS 1e-5f

// ---------------------------------------------------------------------------
// Kernel 1: fused kv-GEMM + BN + per-head key transform + tanh + lattice coords
// ---------------------------------------------------------------------------
__global__ __launch_bounds__(128)
void k_front(const float* __restrict__ x,      // [B,D,N]
             const float* __restrict__ orig,   // [B,3,N]
             const float* __restrict__ wkv,    // [152,64]
             const float* __restrict__ kg, const float* __restrict__ kb,
             const float* __restrict__ km, const float* __restrict__ kvv,
             const float* __restrict__ vg, const float* __restrict__ vb,
             const float* __restrict__ vm, const float* __restrict__ vv,
             const float* __restrict__ Wt,     // [8,3,3]
             const float* __restrict__ bt,     // [8,3]
             float* __restrict__ values,       // [B,H,N,C]
             int*   __restrict__ idxb,         // [B,H,N,8]
             float* __restrict__ wbf)          // [B,H,N,8]
{
    __shared__ float wl[NKV * ND];
    __shared__ float ksc[24], ksh[24], vsc[128], vsh[128], wts[72], bts[24];
    const int tid = threadIdx.x;

    for (int i = tid; i < NKV * ND; i += 128) wl[i] = wkv[i];
    if (tid < 24) {
        float s = rsqrtf(kvv[tid] + KEPS) * kg[tid];
        ksc[tid] = s;
        ksh[tid] = kb[tid] - km[tid] * s;
    }
    if (tid < 128) {
        float s = rsqrtf(vv[tid] + KEPS) * vg[tid];
        vsc[tid] = s;
        vsh[tid] = vb[tid] - vm[tid] * s;
    }
    if (tid < 72) wts[tid] = Wt[tid];
    if (tid < 24) bts[tid] = bt[tid];
    __syncthreads();

    const int bpb = NN / 128;                 // blocks per batch
    const int b = blockIdx.x / bpb;
    const int n = (blockIdx.x % bpb) * 128 + tid;

    float xr[ND];
    #pragma unroll
    for (int d = 0; d < ND; ++d)
        xr[d] = x[((long)b * ND + d) * NN + n];

    // keys: rows 0..23 of kv, BN'd
    float ko[24];
    #pragma unroll 1
    for (int o = 0; o < 24; o += 4) {
        float s0 = 0.f, s1 = 0.f, s2 = 0.f, s3 = 0.f;
        #pragma unroll
        for (int d = 0; d < ND; ++d) {
            float xv = xr[d];
            s0 = fmaf(wl[(o + 0) * ND + d], xv, s0);
            s1 = fmaf(wl[(o + 1) * ND + d], xv, s1);
            s2 = fmaf(wl[(o + 2) * ND + d], xv, s2);
            s3 = fmaf(wl[(o + 3) * ND + d], xv, s3);
        }
        ko[o + 0] = fmaf(s0, ksc[o + 0], ksh[o + 0]);
        ko[o + 1] = fmaf(s1, ksc[o + 1], ksh[o + 1]);
        ko[o + 2] = fmaf(s2, ksc[o + 2], ksh[o + 2]);
        ko[o + 3] = fmaf(s3, ksc[o + 3], ksh[o + 3]);
    }

    // values: rows 24..151 of kv, BN'd, store [B,H,N,C]
    #pragma unroll 1
    for (int oc = 0; oc < 128; oc += 4) {
        float s0 = 0.f, s1 = 0.f, s2 = 0.f, s3 = 0.f;
        #pragma unroll
        for (int d = 0; d < ND; ++d) {
            float xv = xr[d];
            s0 = fmaf(wl[(24 + oc + 0) * ND + d], xv, s0);
            s1 = fmaf(wl[(24 + oc + 1) * ND + d], xv, s1);
            s2 = fmaf(wl[(24 + oc + 2) * ND + d], xv, s2);
            s3 = fmaf(wl[(24 + oc + 3) * ND + d], xv, s3);
        }
        int h = oc >> 4, c = oc & 15;
        float* vp = values + (((long)(b * NH + h) * NN + n) * NC + c);
        vp[0] = fmaf(s0, vsc[oc + 0], vsh[oc + 0]);
        vp[1] = fmaf(s1, vsc[oc + 1], vsh[oc + 1]);
        vp[2] = fmaf(s2, vsc[oc + 2], vsh[oc + 2]);
        vp[3] = fmaf(s3, vsc[oc + 3], vsh[oc + 3]);
    }

    const float o0 = orig[((long)b * 3 + 0) * NN + n];
    const float o1 = orig[((long)b * 3 + 1) * NN + n];
    const float o2 = orig[((long)b * 3 + 2) * NN + n];

    #pragma unroll 1
    for (int h = 0; h < NH; ++h) {
        float p0 = o0 + ko[h * 3 + 0];
        float p1 = o1 + ko[h * 3 + 1];
        float p2 = o2 + ko[h * 3 + 2];
        float t0 = fmaf(wts[h * 9 + 0], p0, fmaf(wts[h * 9 + 1], p1, fmaf(wts[h * 9 + 2], p2, bts[h * 3 + 0])));
        float t1 = fmaf(wts[h * 9 + 3], p0, fmaf(wts[h * 9 + 4], p1, fmaf(wts[h * 9 + 5], p2, bts[h * 3 + 1])));
        float t2 = fmaf(wts[h * 9 + 6], p0, fmaf(wts[h * 9 + 7], p1, fmaf(wts[h * 9 + 8], p2, bts[h * 3 + 2])));
        float l0 = tanhf(t0), l1 = tanhf(t1), l2 = tanhf(t2);
        float pos0 = (l0 + 1.f) * 15.5f;
        float pos1 = (l1 + 1.f) * 15.5f;
        float pos2 = (l2 + 1.f) * 15.5f;
        float b0 = fminf(fmaxf(floorf(pos0), 0.f), 30.f);
        float b1 = fminf(fmaxf(floorf(pos1), 0.f), 30.f);
        float b2 = fminf(fmaxf(floorf(pos2), 0.f), 30.f);
        int ix = (int)b0, iy = (int)b1, iz = (int)b2;
        float fx = pos0 - b0, fy = pos1 - b1, fz = pos2 - b2;
        float gx = 1.f - fx, gy = 1.f - fy, gz = 1.f - fz;
        long base = ((long)(b * NH + h) * NN + n) * 8;
        int ibase = (ix * NG + iy) * NG + iz;
        idxb[base + 0] = ibase;                 wbf[base + 0] = gx * gy * gz;
        idxb[base + 1] = ibase + 1;             wbf[base + 1] = gx * gy * fz;
        idxb[base + 2] = ibase + NG;            wbf[base + 2] = gx * fy * gz;
        idxb[base + 3] = ibase + NG + 1;        wbf[base + 3] = gx * fy * fz;
        idxb[base + 4] = ibase + NG * NG;       wbf[base + 4] = fx * gy * gz;
        idxb[base + 5] = ibase + NG * NG + 1;   wbf[base + 5] = fx * gy * fz;
        idxb[base + 6] = ibase + NG * NG + NG;  wbf[base + 6] = fx * fy * gz;
        idxb[base + 7] = ibase + NG * NG + NG + 1; wbf[base + 7] = fx * fy * fz;
    }
}

// ---------------------------------------------------------------------------
// Kernel 2: splat — weighted scatter-add into grid [B,H,G3,C]
// ---------------------------------------------------------------------------
__global__ __launch_bounds__(256)
void k_splat(const float* __restrict__ values, const int* __restrict__ idxb,
             const float* __restrict__ wbf, float* __restrict__ grid)
{
    long t = (long)blockIdx.x * 256 + threadIdx.x;   // (b*H+h)*N + n
    const float* vrow = values + t * NC;
    float v[NC];
    #pragma unroll
    for (int c = 0; c < NC; ++c) v[c] = vrow[c];
    const int* ip = idxb + t * 8;
    const float* wp = wbf + t * 8;
    long bh = t / NN;
    float* gbase = grid + bh * (long)NG3 * NC;
    #pragma unroll
    for (int ci = 0; ci < 8; ++ci) {
        int idx = ip[ci];
        float w = wp[ci];
        float* gc = gbase + (long)idx * NC;
        #pragma unroll
        for (int c = 0; c < NC; ++c)
            unsafeAtomicAdd(gc + c, v[c] * w);
    }
}

// ---------------------------------------------------------------------------
// Kernel 3: grouped 3x3x3 conv, SAME padding, direct fp32 with LDS tiles
// block: 256 threads = 16 oc x (4x,4y); each thread computes 8 z outputs
// ---------------------------------------------------------------------------
__global__ __launch_bounds__(256)
void k_conv(const float* __restrict__ grid, const float* __restrict__ cw,
            const float* __restrict__ cb, float* __restrict__ convo)
{
    __shared__ float it[16 * 6 * 6 * 10];   // [ic][xx][yy][zz]
    __shared__ float wt[432 * 16];          // [r=ic*27+kx*9+ky*3+kz][oc]
    const int tid = threadIdx.x;
    const int bid = blockIdx.x;
    const int zb = bid & 3, yb = (bid >> 2) & 7, xb = (bid >> 5) & 7;
    const int bh = bid >> 8;
    const int h = bh & 7;

    for (int e = tid; e < 6912; e += 256) {
        int oc = e / 432, r = e % 432;
        wt[r * 16 + oc] = cw[(h * 16 + oc) * 432 + r];
    }
    const float* gbase = grid + (long)bh * NG3 * NC;
    for (int e = tid; e < 5760; e += 256) {
        int ic = e & 15, cell = e >> 4;
        int zz = cell % 10, yy = (cell / 10) % 6, xx = cell / 60;
        int gx = xb * 4 + xx - 1, gy = yb * 4 + yy - 1, gz = zb * 8 + zz - 1;
        float v = 0.f;
        if ((unsigned)gx < NG && (unsigned)gy < NG && (unsigned)gz < NG)
            v = gbase[(((long)gx * NG + gy) * NG + gz) * NC + ic];
        it[ic * 360 + xx * 60 + yy * 10 + zz] = v;
    }
    __syncthreads();

    const int oc = tid & 15, txty = tid >> 4;
    const int tx = txty & 3, ty = txty >> 2;
    float acc[8];
    #pragma unroll
    for (int z = 0; z < 8; ++z) acc[z] = 0.f;

    #pragma unroll 1
    for (int ic = 0; ic < 16; ++ic) {
        #pragma unroll
        for (int kx = 0; kx < 3; ++kx) {
            #pragma unroll
            for (int ky = 0; ky < 3; ++ky) {
                const float* ib = &it[ic * 360 + (tx + kx) * 60 + (ty + ky) * 10];
                const float* wp = &wt[(ic * 27 + kx * 9 + ky * 3) * 16 + oc];
                float w0 = wp[0], w1 = wp[16], w2 = wp[32];
                #pragma unroll
                for (int z = 0; z < 8; ++z)
                    acc[z] = fmaf(ib[z], w0, fmaf(ib[z + 1], w1, fmaf(ib[z + 2], w2, acc[z])));
            }
        }
    }
    float bias = cb[h * 16 + oc];
    int gx = xb * 4 + tx, gy = yb * 4 + ty;
    float* ob = convo + (long)bh * NG3 * NC + (((long)gx * NG + gy) * NG + zb * 8) * NC + oc;
    #pragma unroll
    for (int z = 0; z < 8; ++z) ob[z * NC] = acc[z] + bias;
}

// ---------------------------------------------------------------------------
// Kernel 4: slice (weighted gather) + BN + ReLU, output FLOAT32 [B, H*C, N]
// ---------------------------------------------------------------------------
__global__ __launch_bounds__(256)
void k_slice(const float* __restrict__ convo, const int* __restrict__ idxb,
             const float* __restrict__ wbf,
             const float* __restrict__ ag, const float* __restrict__ ab,
             const float* __restrict__ am, const float* __restrict__ av,
             float* __restrict__ out)
{
    __shared__ float asc[128], ash[128];
    const int tid = threadIdx.x;
    if (tid < 128) {
        float s = rsqrtf(av[tid] + KEPS) * ag[tid];
        asc[tid] = s;
        ash[tid] = ab[tid] - am[tid] * s;
    }
    __syncthreads();

    long t = (long)blockIdx.x * 256 + tid;   // (b*H+h)*N + n
    long bh = t / NN;
    int n = (int)(t % NN);
    int b = (int)(bh >> 3), h = (int)(bh & 7);
    const float* g = convo + bh * (long)NG3 * NC;
    const int* ip = idxb + t * 8;
    const float* wp = wbf + t * 8;

    float acc[NC];
    #pragma unroll
    for (int c = 0; c < NC; ++c) acc[c] = 0.f;
    #pragma unroll
    for (int ci = 0; ci < 8; ++ci) {
        int idx = ip[ci];
        float w = wp[ci];
        const float* gc = g + (long)idx * NC;
        #pragma unroll
        for (int c = 0; c < NC; ++c) acc[c] = fmaf(gc[c], w, acc[c]);
    }
    float* ob = out + ((long)b * 128 + h * 16) * NN + n;
    #pragma unroll
    for (int c = 0; c < NC; ++c) {
        float r = fmaf(acc[c], asc[h * 16 + c], ash[h * 16 + c]);
        ob[(long)c * NN] = fmaxf(r, 0.f);
    }
}

// ---------------------------------------------------------------------------
extern "C" void kernel_launch(void* const* d_in, const int* in_sizes, int n_in,
                              void* d_out, int out_size, void* d_ws, size_t ws_size,
                              hipStream_t stream)
{
    (void)in_sizes; (void)n_in; (void)out_size; (void)ws_size;
    const float* x    = (const float*)d_in[0];
    const float* orig = (const float*)d_in[1];
    const float* wkv  = (const float*)d_in[2];
    const float* kg   = (const float*)d_in[3];
    const float* kb   = (const float*)d_in[4];
    const float* km   = (const float*)d_in[5];
    const float* kvv  = (const float*)d_in[6];
    const float* vg   = (const float*)d_in[7];
    const float* vb   = (const float*)d_in[8];
    const float* vm   = (const float*)d_in[9];
    const float* vv   = (const float*)d_in[10];
    const float* Wt   = (const float*)d_in[11];
    const float* bt   = (const float*)d_in[12];
    const float* cw   = (const float*)d_in[13];
    const float* cb   = (const float*)d_in[14];
    const float* ag   = (const float*)d_in[15];
    const float* ab   = (const float*)d_in[16];
    const float* am   = (const float*)d_in[17];
    const float* av   = (const float*)d_in[18];

    char* ws = (char*)d_ws;
    float* values = (float*)(ws);                    // 33,554,432 B  [B,H,N,C]
    int*   idxb   = (int*)  (ws + 33554432);         // 16,777,216 B  [B,H,N,8]
    float* wbf    = (float*)(ws + 50331648);         // 16,777,216 B  [B,H,N,8]
    float* grid   = (float*)(ws + 67108864);         // 67,108,864 B  [B,H,G3,C]
    float* convo  = (float*)(ws + 134217728);        // 67,108,864 B  [B,H,G3,C]

    k_front<<<dim3((NB * NN) / 128), dim3(128), 0, stream>>>(
        x, orig, wkv, kg, kb, km, kvv, vg, vb, vm, vv, Wt, bt, values, idxb, wbf);

    hipMemsetAsync(grid, 0, (size_t)NB * NH * NG3 * NC * sizeof(float), stream);

    k_splat<<<dim3((NB * NH * NN) / 256), dim3(256), 0, stream>>>(values, idxb, wbf, grid);

    k_conv<<<dim3(NB * NH * 256), dim3(256), 0, stream>>>(grid, cw, cb, convo);

    k_slice<<<dim3((NB * NH * NN) / 256), dim3(256), 0, stream>>>(
        convo, idxb, wbf, ag, ab, am, av, (float*)d_out);
}

// Round 4
// 1059.646 us; speedup vs baseline: 3.8290x; 3.8290x over previous
//
#include <hip/hip_runtime.h>
#include <hip/hip_bf16.h>

#define NB  4
#define NH  8
#define NC  16
#define ND  64
#define NN  16384
#define NG  32
#define NG3 32768
#define NKV 152
#define KEPS 1e-5f

// ---------------------------------------------------------------------------
// Kernel 1: fused kv-GEMM + BN + per-head key transform + tanh + lattice coords
// Emits compact per-(point,head) record: {flat base idx, fx, fy, fz} (16 B).
// ---------------------------------------------------------------------------
__global__ __launch_bounds__(128)
void k_front(const float* __restrict__ x,      // [B,D,N]
             const float* __restrict__ orig,   // [B,3,N]
             const float* __restrict__ wkv,    // [152,64]
             const float* __restrict__ kg, const float* __restrict__ kb,
             const float* __restrict__ km, const float* __restrict__ kvv,
             const float* __restrict__ vg, const float* __restrict__ vb,
             const float* __restrict__ vm, const float* __restrict__ vv,
             const float* __restrict__ Wt,     // [8,3,3]
             const float* __restrict__ bt,     // [8,3]
             float* __restrict__ values,       // [B,H,N,C]
             float4* __restrict__ pre)         // [B,H,N] {ibase,fx,fy,fz}
{
    __shared__ float wl[NKV * ND];
    __shared__ float ksc[24], ksh[24], vsc[128], vsh[128], wts[72], bts[24];
    const int tid = threadIdx.x;

    for (int i = tid; i < NKV * ND; i += 128) wl[i] = wkv[i];
    if (tid < 24) {
        float s = rsqrtf(kvv[tid] + KEPS) * kg[tid];
        ksc[tid] = s;
        ksh[tid] = kb[tid] - km[tid] * s;
    }
    if (tid < 128) {
        float s = rsqrtf(vv[tid] + KEPS) * vg[tid];
        vsc[tid] = s;
        vsh[tid] = vb[tid] - vm[tid] * s;
    }
    if (tid < 72) wts[tid] = Wt[tid];
    if (tid < 24) bts[tid] = bt[tid];
    __syncthreads();

    const int bpb = NN / 128;                 // blocks per batch
    const int b = blockIdx.x / bpb;
    const int n = (blockIdx.x % bpb) * 128 + tid;

    float xr[ND];
    #pragma unroll
    for (int d = 0; d < ND; ++d)
        xr[d] = x[((long)b * ND + d) * NN + n];

    // keys: rows 0..23 of kv, BN'd
    float ko[24];
    #pragma unroll 1
    for (int o = 0; o < 24; o += 4) {
        float s0 = 0.f, s1 = 0.f, s2 = 0.f, s3 = 0.f;
        #pragma unroll
        for (int d = 0; d < ND; ++d) {
            float xv = xr[d];
            s0 = fmaf(wl[(o + 0) * ND + d], xv, s0);
            s1 = fmaf(wl[(o + 1) * ND + d], xv, s1);
            s2 = fmaf(wl[(o + 2) * ND + d], xv, s2);
            s3 = fmaf(wl[(o + 3) * ND + d], xv, s3);
        }
        ko[o + 0] = fmaf(s0, ksc[o + 0], ksh[o + 0]);
        ko[o + 1] = fmaf(s1, ksc[o + 1], ksh[o + 1]);
        ko[o + 2] = fmaf(s2, ksc[o + 2], ksh[o + 2]);
        ko[o + 3] = fmaf(s3, ksc[o + 3], ksh[o + 3]);
    }

    // values: rows 24..151 of kv, BN'd, store [B,H,N,C]
    #pragma unroll 1
    for (int oc = 0; oc < 128; oc += 4) {
        float s0 = 0.f, s1 = 0.f, s2 = 0.f, s3 = 0.f;
        #pragma unroll
        for (int d = 0; d < ND; ++d) {
            float xv = xr[d];
            s0 = fmaf(wl[(24 + oc + 0) * ND + d], xv, s0);
            s1 = fmaf(wl[(24 + oc + 1) * ND + d], xv, s1);
            s2 = fmaf(wl[(24 + oc + 2) * ND + d], xv, s2);
            s3 = fmaf(wl[(24 + oc + 3) * ND + d], xv, s3);
        }
        int h = oc >> 4, c = oc & 15;
        float* vp = values + (((long)(b * NH + h) * NN + n) * NC + c);
        vp[0] = fmaf(s0, vsc[oc + 0], vsh[oc + 0]);
        vp[1] = fmaf(s1, vsc[oc + 1], vsh[oc + 1]);
        vp[2] = fmaf(s2, vsc[oc + 2], vsh[oc + 2]);
        vp[3] = fmaf(s3, vsc[oc + 3], vsh[oc + 3]);
    }

    const float o0 = orig[((long)b * 3 + 0) * NN + n];
    const float o1 = orig[((long)b * 3 + 1) * NN + n];
    const float o2 = orig[((long)b * 3 + 2) * NN + n];

    #pragma unroll 1
    for (int h = 0; h < NH; ++h) {
        float p0 = o0 + ko[h * 3 + 0];
        float p1 = o1 + ko[h * 3 + 1];
        float p2 = o2 + ko[h * 3 + 2];
        float t0 = fmaf(wts[h * 9 + 0], p0, fmaf(wts[h * 9 + 1], p1, fmaf(wts[h * 9 + 2], p2, bts[h * 3 + 0])));
        float t1 = fmaf(wts[h * 9 + 3], p0, fmaf(wts[h * 9 + 4], p1, fmaf(wts[h * 9 + 5], p2, bts[h * 3 + 1])));
        float t2 = fmaf(wts[h * 9 + 6], p0, fmaf(wts[h * 9 + 7], p1, fmaf(wts[h * 9 + 8], p2, bts[h * 3 + 2])));
        float l0 = tanhf(t0), l1 = tanhf(t1), l2 = tanhf(t2);
        float pos0 = (l0 + 1.f) * 15.5f;
        float pos1 = (l1 + 1.f) * 15.5f;
        float pos2 = (l2 + 1.f) * 15.5f;
        float b0 = fminf(fmaxf(floorf(pos0), 0.f), 30.f);
        float b1 = fminf(fmaxf(floorf(pos1), 0.f), 30.f);
        float b2 = fminf(fmaxf(floorf(pos2), 0.f), 30.f);
        int ix = (int)b0, iy = (int)b1, iz = (int)b2;
        float fx = pos0 - b0, fy = pos1 - b1, fz = pos2 - b2;
        int ibase = (ix * NG + iy) * NG + iz;
        float4 pr;
        pr.x = __int_as_float(ibase);
        pr.y = fx; pr.z = fy; pr.w = fz;
        pre[(long)(b * NH + h) * NN + n] = pr;
    }
}

// ---------------------------------------------------------------------------
// Kernel 2: splat — each block owns one grid x-plane of one (b,h).
// Streams all point records, accumulates in-plane corners in LDS (rotated
// channel layout to spread banks), writes the plane once. No global atomics.
// ---------------------------------------------------------------------------
__global__ __launch_bounds__(256)
void k_splat2(const float* __restrict__ values, const float4* __restrict__ pre,
              float* __restrict__ grid)
{
    __shared__ float sg[NG * NG * NC];   // 64 KB: [y*32+z][c] with c rotated by cell
    const int tid = threadIdx.x;
    const int rx = blockIdx.x & 31;
    const int bh = blockIdx.x >> 5;

    for (int i = tid; i < NG * NG * NC; i += 256) sg[i] = 0.f;
    __syncthreads();

    const float4* pp = pre + (long)bh * NN;
    const float*  vbp = values + (long)bh * NN * NC;

    for (int n = tid; n < NN; n += 256) {
        float4 r = pp[n];
        int ibase = __float_as_int(r.x);
        int ix = ibase >> 10;
        int lo = ibase & 1023;           // iy*32+iz
        float fx = r.y, fy = r.z, fz = r.w;
        float wx;
        if (ix == rx)          wx = 1.f - fx;
        else if (ix + 1 == rx) wx = fx;
        else continue;
        float gy = 1.f - fy, gz = 1.f - fz;
        float w00 = wx * gy * gz;
        float w01 = wx * gy * fz;
        float w10 = wx * fy * gz;
        float w11 = wx * fy * fz;
        const float4* vr = (const float4*)(vbp + (long)n * NC);
        float4 v0 = vr[0], v1 = vr[1], v2 = vr[2], v3 = vr[3];
        float v[16];
        ((float4*)v)[0] = v0; ((float4*)v)[1] = v1;
        ((float4*)v)[2] = v2; ((float4*)v)[3] = v3;
        const int L00 = lo, L01 = lo + 1, L10 = lo + 32, L11 = lo + 33;
        #pragma unroll
        for (int c = 0; c < 16; ++c) {
            float vc = v[c];
            atomicAdd(&sg[(L00 << 4) | ((c + L00) & 15)], vc * w00);
            atomicAdd(&sg[(L01 << 4) | ((c + L01) & 15)], vc * w01);
            atomicAdd(&sg[(L10 << 4) | ((c + L10) & 15)], vc * w10);
            atomicAdd(&sg[(L11 << 4) | ((c + L11) & 15)], vc * w11);
        }
    }
    __syncthreads();

    float* gb = grid + ((long)bh * NG3 + rx * (NG * NG)) * NC;
    for (int i = tid; i < NG * NG * NC; i += 256) {
        int L = i >> 4, c = i & 15;
        gb[i] = sg[(L << 4) | ((c + L) & 15)];
    }
}

// ---------------------------------------------------------------------------
// Kernel 3: grouped 3x3x3 conv, SAME padding, direct fp32 with LDS tiles
// block: 256 threads = 16 oc x (4x,4y); each thread computes 8 z outputs
// ---------------------------------------------------------------------------
__global__ __launch_bounds__(256)
void k_conv(const float* __restrict__ grid, const float* __restrict__ cw,
            const float* __restrict__ cb, float* __restrict__ convo)
{
    __shared__ float it[16 * 6 * 6 * 10];   // [ic][xx][yy][zz]
    __shared__ float wt[432 * 16];          // [r=ic*27+kx*9+ky*3+kz][oc]
    const int tid = threadIdx.x;
    const int bid = blockIdx.x;
    const int zb = bid & 3, yb = (bid >> 2) & 7, xb = (bid >> 5) & 7;
    const int bh = bid >> 8;
    const int h = bh & 7;

    for (int e = tid; e < 6912; e += 256) {
        int oc = e / 432, r = e % 432;
        wt[r * 16 + oc] = cw[(h * 16 + oc) * 432 + r];
    }
    const float* gbase = grid + (long)bh * NG3 * NC;
    for (int e = tid; e < 5760; e += 256) {
        int ic = e & 15, cell = e >> 4;
        int zz = cell % 10, yy = (cell / 10) % 6, xx = cell / 60;
        int gx = xb * 4 + xx - 1, gy = yb * 4 + yy - 1, gz = zb * 8 + zz - 1;
        float v = 0.f;
        if ((unsigned)gx < NG && (unsigned)gy < NG && (unsigned)gz < NG)
            v = gbase[(((long)gx * NG + gy) * NG + gz) * NC + ic];
        it[ic * 360 + xx * 60 + yy * 10 + zz] = v;
    }
    __syncthreads();

    const int oc = tid & 15, txty = tid >> 4;
    const int tx = txty & 3, ty = txty >> 2;
    float acc[8];
    #pragma unroll
    for (int z = 0; z < 8; ++z) acc[z] = 0.f;

    #pragma unroll 1
    for (int ic = 0; ic < 16; ++ic) {
        #pragma unroll
        for (int kx = 0; kx < 3; ++kx) {
            #pragma unroll
            for (int ky = 0; ky < 3; ++ky) {
                const float* ib = &it[ic * 360 + (tx + kx) * 60 + (ty + ky) * 10];
                const float* wp = &wt[(ic * 27 + kx * 9 + ky * 3) * 16 + oc];
                float w0 = wp[0], w1 = wp[16], w2 = wp[32];
                #pragma unroll
                for (int z = 0; z < 8; ++z)
                    acc[z] = fmaf(ib[z], w0, fmaf(ib[z + 1], w1, fmaf(ib[z + 2], w2, acc[z])));
            }
        }
    }
    float bias = cb[h * 16 + oc];
    int gx = xb * 4 + tx, gy = yb * 4 + ty;
    float* ob = convo + (long)bh * NG3 * NC + (((long)gx * NG + gy) * NG + zb * 8) * NC + oc;
    #pragma unroll
    for (int z = 0; z < 8; ++z) ob[z * NC] = acc[z] + bias;
}

// ---------------------------------------------------------------------------
// Kernel 4: slice (weighted gather) + BN + ReLU, output FLOAT32 [B, H*C, N]
// ---------------------------------------------------------------------------
__global__ __launch_bounds__(256)
void k_slice(const float* __restrict__ convo, const float4* __restrict__ pre,
             const float* __restrict__ ag, const float* __restrict__ ab,
             const float* __restrict__ am, const float* __restrict__ av,
             float* __restrict__ out)
{
    __shared__ float asc[128], ash[128];
    const int tid = threadIdx.x;
    if (tid < 128) {
        float s = rsqrtf(av[tid] + KEPS) * ag[tid];
        asc[tid] = s;
        ash[tid] = ab[tid] - am[tid] * s;
    }
    __syncthreads();

    long t = (long)blockIdx.x * 256 + tid;   // (b*H+h)*N + n
    long bh = t / NN;
    int n = (int)(t % NN);
    int b = (int)(bh >> 3), h = (int)(bh & 7);
    const float* g = convo + bh * (long)NG3 * NC;

    float4 r = pre[t];
    int ibase = __float_as_int(r.x);
    float fx = r.y, fy = r.z, fz = r.w;
    float gx = 1.f - fx, gy = 1.f - fy, gz = 1.f - fz;
    const float ws8[8] = {gx*gy*gz, gx*gy*fz, gx*fy*gz, gx*fy*fz,
                          fx*gy*gz, fx*gy*fz, fx*fy*gz, fx*fy*fz};
    const int offs[8] = {0, 1, NG, NG + 1, NG*NG, NG*NG + 1, NG*NG + NG, NG*NG + NG + 1};

    float acc[NC];
    #pragma unroll
    for (int c = 0; c < NC; ++c) acc[c] = 0.f;
    #pragma unroll
    for (int ci = 0; ci < 8; ++ci) {
        float w = ws8[ci];
        const float* gc = g + (long)(ibase + offs[ci]) * NC;
        #pragma unroll
        for (int c = 0; c < NC; ++c) acc[c] = fmaf(gc[c], w, acc[c]);
    }
    float* ob = out + ((long)b * 128 + h * 16) * NN + n;
    #pragma unroll
    for (int c = 0; c < NC; ++c) {
        float rr = fmaf(acc[c], asc[h * 16 + c], ash[h * 16 + c]);
        ob[(long)c * NN] = fmaxf(rr, 0.f);
    }
}

// ---------------------------------------------------------------------------
extern "C" void kernel_launch(void* const* d_in, const int* in_sizes, int n_in,
                              void* d_out, int out_size, void* d_ws, size_t ws_size,
                              hipStream_t stream)
{
    (void)in_sizes; (void)n_in; (void)out_size; (void)ws_size;
    const float* x    = (const float*)d_in[0];
    const float* orig = (const float*)d_in[1];
    const float* wkv  = (const float*)d_in[2];
    const float* kg   = (const float*)d_in[3];
    const float* kb   = (const float*)d_in[4];
    const float* km   = (const float*)d_in[5];
    const float* kvv  = (const float*)d_in[6];
    const float* vg   = (const float*)d_in[7];
    const float* vb   = (const float*)d_in[8];
    const float* vm   = (const float*)d_in[9];
    const float* vv   = (const float*)d_in[10];
    const float* Wt   = (const float*)d_in[11];
    const float* bt   = (const float*)d_in[12];
    const float* cw   = (const float*)d_in[13];
    const float* cb   = (const float*)d_in[14];
    const float* ag   = (const float*)d_in[15];
    const float* ab   = (const float*)d_in[16];
    const float* am   = (const float*)d_in[17];
    const float* av   = (const float*)d_in[18];

    char* ws = (char*)d_ws;
    float*  values = (float*) (ws);                    // 33,554,432 B  [B,H,N,C]
    float4* pre    = (float4*)(ws + 33554432);         //  8,388,608 B  [B,H,N]
    float*  grid   = (float*) (ws + 41943040);         // 67,108,864 B  [B,H,G3,C]
    float*  convo  = (float*) (ws + 109051904);        // 67,108,864 B  [B,H,G3,C]

    k_front<<<dim3((NB * NN) / 128), dim3(128), 0, stream>>>(
        x, orig, wkv, kg, kb, km, kvv, vg, vb, vm, vv, Wt, bt, values, pre);

    k_splat2<<<dim3(NB * NH * NG), dim3(256), 0, stream>>>(values, pre, grid);

    k_conv<<<dim3(NB * NH * 256), dim3(256), 0, stream>>>(grid, cw, cb, convo);

    k_slice<<<dim3((NB * NH * NN) / 256), dim3(256), 0, stream>>>(
        convo, pre, ag, ab, am, av, (float*)d_out);
}